// Round 8
// baseline (629.364 us; speedup 1.0000x reference)
//
#include <hip/hip_runtime.h>
#include <hip/hip_bf16.h>
#include <math.h>

#define NP 65536
#define HD 128
#define TSTEPS 50

typedef short bf16x8 __attribute__((ext_vector_type(8)));
typedef float f32x4 __attribute__((ext_vector_type(4)));
typedef float f32x2 __attribute__((ext_vector_type(2)));

__device__ __forceinline__ short f2bf(float f) {
    union { float f; unsigned u; } v; v.f = f;
    unsigned r = v.u + 0x7fffu + ((v.u >> 16) & 1u);
    return (short)(r >> 16);
}
// packed pair -> one dword of 2 bf16 (low = a, high = b)
__device__ __forceinline__ unsigned cvt_pk_bf16(float a, float b) {
    __hip_bfloat162 h = __float22bfloat162_rn(make_float2(a, b));
    unsigned u;
    __builtin_memcpy(&u, &h, sizeof(u));
    return u;
}

// ---- packed fp32 math expressed as C vector ops: the backend selects
// v_pk_{fma,add,mul}_f32 on gfx950 (PackedFP32Ops); semantics guaranteed.
__device__ __forceinline__ f32x2 pk_fma(f32x2 a, f32x2 b, f32x2 c) {
    return __builtin_elementwise_fma(a, b, c);
}
__device__ __forceinline__ f32x2 pk_add(f32x2 a, f32x2 b) { return a + b; }
__device__ __forceinline__ f32x2 pk_mul(f32x2 a, f32x2 b) { return a * b; }
__device__ __forceinline__ f32x2 pk_max(f32x2 a, f32x2 b) {
    return __builtin_elementwise_max(a, b);
}

// packed tanh: 1 - 2/(exp2(2x*log2e)+1); saturates via inf/0, no clamps
__device__ __forceinline__ f32x2 tanh_pk(f32x2 x, f32x2 k2, f32x2 one2, f32x2 m2) {
    f32x2 t = pk_mul(x, k2);
    f32x2 e;
    e.x = __builtin_amdgcn_exp2f(t.x);
    e.y = __builtin_amdgcn_exp2f(t.y);
    f32x2 dn = pk_add(e, one2);
    f32x2 r;
    r.x = __builtin_amdgcn_rcpf(dn.x);
    r.y = __builtin_amdgcn_rcpf(dn.y);
    return pk_fma(r, m2, one2);
}

// ---------------------------------------------------------------------------
// Per-step tables; one block per step i.
// ---------------------------------------------------------------------------
__global__ __launch_bounds__(128) void prep_kernel(
    const float* __restrict__ times, const float* __restrict__ freqs,
    const float* __restrict__ log_diff,
    const float* __restrict__ W1, const float* __restrict__ b1,
    const float* __restrict__ V1, const float* __restrict__ c1,
    float* __restrict__ tembW, float* __restrict__ tV,
    float* __restrict__ dtv, float* __restrict__ nsv)
{
    int j = threadIdx.x;
    int i = blockIdx.x;
    float ld = log_diff[0];
    float gb = (ld > 20.0f) ? ld : log1pf(expf(ld));  // softplus
    float t  = times[i];
    float dt = times[i + 1] - t;
    float acc = b1[j];
    #pragma unroll
    for (int m = 0; m < 16; ++m) {
        float a = 6.283185307179586f * t * freqs[m];
        float sn, cs;
        sincosf(a, &sn, &cs);
        acc = fmaf(sn, W1[(130 + m) * HD + j], acc);
        acc = fmaf(cs, W1[(146 + m) * HD + j], acc);
    }
    tembW[i * HD + j] = acc;
    tV[i * HD + j] = fmaf(t, V1[130 * HD + j], c1[j]);
    if (j == 0) {
        dtv[i] = dt;
        nsv[i] = gb * (1.0f - t) * sqrtf(fmaxf(dt, 1e-12f));
    }
}

// ---------------------------------------------------------------------------
// Pack 4 weight matrices (W1ctx, V1ctx, W2, V2) into bf16 B-fragment order:
// frag idx = ((jt*4+kt)*4+q)*16+c, element j;  k = kt*32+q*8+j, n = jt*16+c.
// (Identical A/B fragment lane maps on gfx950 mean the same data also serves
//  as the A-operand of W^T — used by the swapped L2 MFMAs in sde_kernel.)
// ---------------------------------------------------------------------------
__global__ __launch_bounds__(256) void pack_kernel(
    const float* __restrict__ W1, const float* __restrict__ V1,
    const float* __restrict__ W2, const float* __restrict__ V2,
    short* __restrict__ packed)
{
    int gi = blockIdx.x * 256 + threadIdx.x;   // 0..65535
    int mat = gi >> 14;
    int s = gi & 16383;
    int j  = s & 7;
    int cc = (s >> 3) & 15;
    int qq = (s >> 7) & 3;
    int kt = (s >> 9) & 3;
    int jt = (s >> 11) & 7;
    int k = kt * 32 + qq * 8 + j;
    int n = jt * 16 + cc;
    float v;
    if      (mat == 0) v = W1[(2 + k) * HD + n];
    else if (mat == 1) v = V1[(2 + k) * HD + n];
    else if (mat == 2) v = W2[k * HD + n];
    else               v = V2[k * HD + n];
    packed[gi] = f2bf(v);
}

// ---------------------------------------------------------------------------
// Persistent SDE kernel.  R16 = R15 + swapped-operand L2 MFMAs:
//   mfma(Wfrag, af) computes h2^T -> output col = PARTICLE = lane c,
//   row = hidden j2 = q*4+r.  (A/B fragments share the same lane map, so
//   the existing packed W2/V2 serve as W^T A-operands unchanged; per-element
//   products and k-order identical -> bitwise-same h2.)
// Buys: lane-aligned epilogue.  Deleted per step: 12-shuffle reduce-scatter
// (-> 2 shfl), zox gather, store shuffle, z re-broadcast (z stays in place),
// 2 bias pk_adds per jt (bias enters as MFMA C-input float4).
// ---------------------------------------------------------------------------
__global__ __launch_bounds__(256, 2) void sde_kernel(
    const float* __restrict__ z0, const float* __restrict__ pctx,
    const float* __restrict__ cctx, const float* __restrict__ xi,
    const short* __restrict__ packedW,
    const float* __restrict__ W1, const float* __restrict__ V1,
    const float* __restrict__ b2, const float* __restrict__ c2,
    const float* __restrict__ W3, const float* __restrict__ b3,
    const float* __restrict__ V3, const float* __restrict__ c3,
    const float* __restrict__ tembW, const float* __restrict__ tV,
    const float* __restrict__ dtv, const float* __restrict__ nsv,
    float* __restrict__ out)
{
    __shared__ char smem[80896];            // 66K frag/stg + 5K tables + 8K tslots
    float* stg = (float*)smem;
    const bf16x8* ldsF = (const bf16x8*)smem;
    float*  zwP0s = (float*)(smem + 67584);   // W1 row0 (z.x weights), fp32
    float*  zwP1s = (float*)(smem + 68096);   // W1 row1
    float*  zwC0s = (float*)(smem + 68608);   // V1 row0
    float*  zwC1s = (float*)(smem + 69120);   // V1 row1
    float*  b2s   = (float*)(smem + 69632);
    float*  c2s   = (float*)(smem + 70144);
    float2* w3s   = (float2*)(smem + 70656);
    float2* v3s   = (float2*)(smem + 71680);

    int tid = threadIdx.x;
    int lane = tid & 63, wv = tid >> 6;
    int q = lane >> 4, c = lane & 15;
    int m0 = blockIdx.x * 64 + wv * 16;     // wave's 16-row base
    int mrow = m0 + c;                      // this lane's A-layout row

    // per-wave table slot: 2 buffers x 256 floats (tV[0:128] ++ tembW[128:256])
    float* tslot = (float*)(smem + 72704) + wv * 512;

    // ---- small constant tables -> LDS (covered by the phase-1 barrier) ----
    if (tid < 128) {
        zwP0s[tid] = W1[tid];
        zwP1s[tid] = W1[HD + tid];
        zwC0s[tid] = V1[tid];
        zwC1s[tid] = V1[HD + tid];
        b2s[tid] = b2[tid];
        c2s[tid] = c2[tid];
        w3s[tid] = ((const float2*)W3)[tid];
        v3s[tid] = ((const float2*)V3)[tid];
    }

    // ---- phase 1: W1ctx/V1ctx fragments -> LDS (coalesced copy) ----
    {
        const uint4* src = (const uint4*)packedW;   // mats 0,1 = 64 KB
        uint4* dst = (uint4*)smem;
        #pragma unroll
        for (int i = 0; i < 16; ++i) dst[i * 256 + tid] = src[i * 256 + tid];
    }
    __syncthreads();

    // ---- ctx A-fragments ----
    bf16x8 pf[4], cf[4];
    #pragma unroll
    for (int kt = 0; kt < 4; ++kt) {
        const float4* p4 = (const float4*)(pctx + (size_t)mrow * HD + kt * 32 + q * 8);
        float4 a = p4[0], b = p4[1];
        uint4 tu;
        tu.x = cvt_pk_bf16(a.x, a.y); tu.y = cvt_pk_bf16(a.z, a.w);
        tu.z = cvt_pk_bf16(b.x, b.y); tu.w = cvt_pk_bf16(b.z, b.w);
        __builtin_memcpy(&pf[kt], &tu, 16);
        const float4* c4 = (const float4*)(cctx + (size_t)mrow * HD + kt * 32 + q * 8);
        float4 e = c4[0], d = c4[1];
        uint4 uu;
        uu.x = cvt_pk_bf16(e.x, e.y); uu.y = cvt_pk_bf16(e.z, e.w);
        uu.z = cvt_pk_bf16(d.x, d.y); uu.w = cvt_pk_bf16(d.z, d.w);
        __builtin_memcpy(&cf[kt], &uu, 16);
    }

    // ---- ctx projection MFMAs (step-invariant) ----
    f32x4 accP[8], accC[8];
    #pragma unroll
    for (int jt = 0; jt < 8; ++jt) {
        f32x4 ap = {0.f,0.f,0.f,0.f}, ac = {0.f,0.f,0.f,0.f};
        #pragma unroll
        for (int kt = 0; kt < 4; ++kt) {
            int fi = ((jt * 4 + kt) * 4 + q) * 16 + c;
            ap = __builtin_amdgcn_mfma_f32_16x16x32_bf16(pf[kt], ldsF[fi], ap, 0, 0, 0);
            ac = __builtin_amdgcn_mfma_f32_16x16x32_bf16(cf[kt], ldsF[2048 + fi], ac, 0, 0, 0);
        }
        accP[jt] = ap; accC[jt] = ac;
    }
    __syncthreads();

    // ---- C-layout -> A-layout round trip through LDS (once) ----
    #pragma unroll
    for (int jt = 0; jt < 8; ++jt)
        #pragma unroll
        for (int r = 0; r < 4; ++r) {
            stg[(wv * 16 + q * 4 + r) * 132 + jt * 16 + c]        = accP[jt][r];
            stg[8448 + (wv * 16 + q * 4 + r) * 132 + jt * 16 + c] = accC[jt][r];
        }
    __syncthreads();
    f32x2 projPf[16], projCf[16];   // fp32 pairs (no per-step unpack)
    #pragma unroll
    for (int kt = 0; kt < 4; ++kt) {
        const float4* rp = (const float4*)(stg + (wv * 16 + c) * 132 + kt * 32 + q * 8);
        float4 a = rp[0], b = rp[1];
        projPf[kt*4+0] = (f32x2){a.x, a.y}; projPf[kt*4+1] = (f32x2){a.z, a.w};
        projPf[kt*4+2] = (f32x2){b.x, b.y}; projPf[kt*4+3] = (f32x2){b.z, b.w};
        const float4* rc = (const float4*)(stg + 8448 + (wv * 16 + c) * 132 + kt * 32 + q * 8);
        float4 e = rc[0], d = rc[1];
        projCf[kt*4+0] = (f32x2){e.x, e.y}; projCf[kt*4+1] = (f32x2){e.z, e.w};
        projCf[kt*4+2] = (f32x2){d.x, d.y}; projCf[kt*4+3] = (f32x2){d.z, d.w};
    }
    __syncthreads();

    // ---- phase 3: W2/V2 fragments -> LDS (resident for all 50 steps) ----
    {
        const uint4* src = (const uint4*)(packedW + 32768);  // mats 2,3
        uint4* dst = (uint4*)smem;
        #pragma unroll
        for (int i = 0; i < 16; ++i) dst[i * 256 + tid] = src[i * 256 + tid];
    }
    __syncthreads();

    float b3x = b3[0] + c3[0], b3y = b3[1] + c3[1];
    const f32x2 k2    = {2.8853900817779268f, 2.8853900817779268f};
    const f32x2 one2  = {1.0f, 1.0f};
    const f32x2 m2    = {-2.0f, -2.0f};
    const f32x2 zero2 = {0.0f, 0.0f};

    const float2* z02 = (const float2*)z0;
    const float2* xi2 = (const float2*)xi;
    float2* out2 = (float2*)out;

    // ---- stage step-0 tables into buf 0 (wave-private, no barrier) ----
    {
        const float4* srcp = (lane < 32)
            ? ((const float4*)(tV) + lane)
            : ((const float4*)(tembW) + (lane - 32));
        *((float4*)tslot + lane) = *srcp;
    }

    float2 zi = z02[mrow];
    float zx = zi.x, zy = zi.y;          // z for particle c (all 4 q-copies)
    if (lane < 16) out2[m0 + lane] = make_float2(zx, zy);   // lane l holds row l

    for (int i = 0; i < TSTEPS; ++i) {
        int b = i & 1;
        const float* tb = tslot + b * 256;

        // prefetch next step's table slice (consumed at end of step)
        int sN = (i + 1 < TSTEPS) ? i + 1 : i;
        float4 pfv;
        {
            const float4* srcp = (lane < 32)
                ? ((const float4*)(tV + sN * HD) + lane)
                : ((const float4*)(tembW + sN * HD) + (lane - 32));
            pfv = *srcp;
        }
        // xi + step scalars, hoisted (particle c; 4 q-copies load same addr)
        float dt = dtv[i], ns = nsv[i];
        float2 xiv = xi2[(size_t)i * NP + m0 + c];

        f32x2 zx2 = {zx, zx}, zy2 = {zy, zy};
        f32x2 px2 = zero2, py2 = zero2;   // particle-c drift partials (pairs)

        // ===== cnf MLP: tanh, V-weights (LDS slot 1) =====
        bf16x8 af[4];
        #pragma unroll
        for (int kt = 0; kt < 4; ++kt) {
            const f32x2* tvp = (const f32x2*)(tb + kt * 32 + q * 8);
            const f32x2* w0p = (const f32x2*)(zwC0s + kt * 32 + q * 8);
            const f32x2* w1p = (const f32x2*)(zwC1s + kt * 32 + q * 8);
            uint4 tu;
            unsigned uu[4];
            #pragma unroll
            for (int p = 0; p < 4; ++p) {
                f32x2 lin = pk_add(projCf[kt * 4 + p], tvp[p]);
                lin = pk_fma(zx2, w0p[p], lin);
                lin = pk_fma(zy2, w1p[p], lin);
                f32x2 th = tanh_pk(lin, k2, one2, m2);
                uu[p] = cvt_pk_bf16(th.x, th.y);
            }
            tu.x = uu[0]; tu.y = uu[1]; tu.z = uu[2]; tu.w = uu[3];
            __builtin_memcpy(&af[kt], &tu, 16);
        }
        #pragma unroll
        for (int jt = 0; jt < 8; ++jt) {
            // swapped operands: h2^T; rows j2 = jt*16+q*4+r, col = particle c.
            // bias c2 enters as C-input (row-indexed float4).
            const float4 cb4 = *(const float4*)(c2s + jt * 16 + q * 4);
            f32x4 acc = {cb4.x, cb4.y, cb4.z, cb4.w};
            #pragma unroll
            for (int kt = 0; kt < 4; ++kt)
                acc = __builtin_amdgcn_mfma_f32_16x16x32_bf16(
                    ldsF[2048 + ((jt * 4 + kt) * 4 + q) * 16 + c], af[kt], acc, 0, 0, 0);
            f32x2 h01 = tanh_pk((f32x2){acc[0], acc[1]}, k2, one2, m2);
            f32x2 h23 = tanh_pk((f32x2){acc[2], acc[3]}, k2, one2, m2);
            const float2* vp = v3s + jt * 16 + q * 4;   // v3 rows j2..j2+3
            float2 v0 = vp[0], v1 = vp[1], v2 = vp[2], v3v = vp[3];
            f32x2 vx01 = {v0.x, v1.x}, vx23 = {v2.x, v3v.x};
            f32x2 vy01 = {v0.y, v1.y}, vy23 = {v2.y, v3v.y};
            px2 = pk_fma(h01, vx01, px2); px2 = pk_fma(h23, vx23, px2);
            py2 = pk_fma(h01, vy01, py2); py2 = pk_fma(h23, vy23, py2);
        }

        // ===== post MLP: relu, W-weights (LDS slot 0) =====
        #pragma unroll
        for (int kt = 0; kt < 4; ++kt) {
            const f32x2* tvp = (const f32x2*)(tb + 128 + kt * 32 + q * 8);
            const f32x2* w0p = (const f32x2*)(zwP0s + kt * 32 + q * 8);
            const f32x2* w1p = (const f32x2*)(zwP1s + kt * 32 + q * 8);
            uint4 tu;
            unsigned uu[4];
            #pragma unroll
            for (int p = 0; p < 4; ++p) {
                f32x2 lin = pk_add(projPf[kt * 4 + p], tvp[p]);
                lin = pk_fma(zx2, w0p[p], lin);
                lin = pk_fma(zy2, w1p[p], lin);
                f32x2 th = pk_max(lin, zero2);
                uu[p] = cvt_pk_bf16(th.x, th.y);
            }
            tu.x = uu[0]; tu.y = uu[1]; tu.z = uu[2]; tu.w = uu[3];
            __builtin_memcpy(&af[kt], &tu, 16);
        }
        #pragma unroll
        for (int jt = 0; jt < 8; ++jt) {
            const float4 bb4 = *(const float4*)(b2s + jt * 16 + q * 4);
            f32x4 acc = {bb4.x, bb4.y, bb4.z, bb4.w};
            #pragma unroll
            for (int kt = 0; kt < 4; ++kt)
                acc = __builtin_amdgcn_mfma_f32_16x16x32_bf16(
                    ldsF[((jt * 4 + kt) * 4 + q) * 16 + c], af[kt], acc, 0, 0, 0);
            f32x2 h01 = pk_max((f32x2){acc[0], acc[1]}, zero2);
            f32x2 h23 = pk_max((f32x2){acc[2], acc[3]}, zero2);
            const float2* wp = w3s + jt * 16 + q * 4;   // w3 rows j2..j2+3
            float2 w0 = wp[0], w1 = wp[1], w2 = wp[2], w3v = wp[3];
            f32x2 wx01 = {w0.x, w1.x}, wx23 = {w2.x, w3v.x};
            f32x2 wy01 = {w0.y, w1.y}, wy23 = {w2.y, w3v.y};
            px2 = pk_fma(h01, wx01, px2); px2 = pk_fma(h23, wx23, px2);
            py2 = pk_fma(h01, wy01, py2); py2 = pk_fma(h23, wy23, py2);
        }

        // write prefetched tables to the other buffer (global load had the
        // whole step to land; next iteration's ds_reads sync via lgkmcnt)
        *((float4*)(tslot + (b ^ 1) * 256) + lane) = pfv;

        // ===== reduce over the 4 q-copies (lanes c, 16+c, 32+c, 48+c) =====
        float sdx = px2.x + px2.y + b3x;
        float sdy = py2.x + py2.y + b3y;
        sdx += __shfl_xor(sdx, 16);
        sdy += __shfl_xor(sdy, 16);
        sdx += __shfl_xor(sdx, 32);
        sdy += __shfl_xor(sdy, 32);

        // ===== z update: lane c holds particle c; all q-copies identical ====
        float znx = fmaf(sdx, dt, zx) + xiv.x * ns;
        float zny = fmaf(sdy, dt, zy) + xiv.y * ns;
        if (lane < 16) out2[(size_t)(i + 1) * NP + m0 + lane] = make_float2(znx, zny);
        zx = znx;
        zy = zny;
    }
}

extern "C" void kernel_launch(void* const* d_in, const int* in_sizes, int n_in,
                              void* d_out, int out_size, void* d_ws, size_t ws_size,
                              hipStream_t stream)
{
    const float* z0    = (const float*)d_in[0];
    const float* pctx  = (const float*)d_in[1];
    const float* cctx  = (const float*)d_in[2];
    const float* times = (const float*)d_in[3];
    const float* xi    = (const float*)d_in[4];
    const float* freqs = (const float*)d_in[5];
    const float* logd  = (const float*)d_in[6];
    const float* W1 = (const float*)d_in[7];
    const float* b1 = (const float*)d_in[8];
    const float* W2 = (const float*)d_in[9];
    const float* b2 = (const float*)d_in[10];
    const float* W3 = (const float*)d_in[11];
    const float* b3 = (const float*)d_in[12];
    const float* V1 = (const float*)d_in[13];
    const float* c1 = (const float*)d_in[14];
    const float* V2 = (const float*)d_in[15];
    const float* c2 = (const float*)d_in[16];
    const float* V3 = (const float*)d_in[17];
    const float* c3 = (const float*)d_in[18];

    short* packedW = (short*)d_ws;                       // 4 x 16384 shorts = 128 KB
    float* tembW = (float*)((char*)d_ws + 131072);       // [50][128]
    float* tV    = tembW + TSTEPS * HD;                  // [50][128]
    float* dtv   = tV + TSTEPS * HD;
    float* nsv   = dtv + 64;

    prep_kernel<<<TSTEPS, 128, 0, stream>>>(times, freqs, logd, W1, b1, V1, c1,
                                            tembW, tV, dtv, nsv);
    pack_kernel<<<256, 256, 0, stream>>>(W1, V1, W2, V2, packedW);
    sde_kernel<<<NP / 64, 256, 0, stream>>>(z0, pctx, cctx, xi, packedW,
                                            W1, V1, b2, c2, W3, b3, V3, c3,
                                            tembW, tV, dtv, nsv,
                                            (float*)d_out);
}

// Round 10
// 590.376 us; speedup vs baseline: 1.0660x; 1.0660x over previous
//
#include <hip/hip_runtime.h>
#include <hip/hip_bf16.h>
#include <math.h>

#define NP 65536
#define HD 128
#define TSTEPS 50

typedef short bf16x8 __attribute__((ext_vector_type(8)));
typedef float f32x4 __attribute__((ext_vector_type(4)));
typedef float f32x2 __attribute__((ext_vector_type(2)));

__device__ __forceinline__ short f2bf(float f) {
    union { float f; unsigned u; } v; v.f = f;
    unsigned r = v.u + 0x7fffu + ((v.u >> 16) & 1u);
    return (short)(r >> 16);
}
// packed pair -> one dword of 2 bf16 (low = a, high = b)
__device__ __forceinline__ unsigned cvt_pk_bf16(float a, float b) {
    __hip_bfloat162 h = __float22bfloat162_rn(make_float2(a, b));
    unsigned u;
    __builtin_memcpy(&u, &h, sizeof(u));
    return u;
}

// ---- packed fp32 math expressed as C vector ops: the backend selects
// v_pk_{fma,add,mul}_f32 on gfx950 (PackedFP32Ops); semantics guaranteed.
__device__ __forceinline__ f32x2 pk_fma(f32x2 a, f32x2 b, f32x2 c) {
    return __builtin_elementwise_fma(a, b, c);
}
__device__ __forceinline__ f32x2 pk_add(f32x2 a, f32x2 b) { return a + b; }
__device__ __forceinline__ f32x2 pk_mul(f32x2 a, f32x2 b) { return a * b; }
__device__ __forceinline__ f32x2 pk_max(f32x2 a, f32x2 b) {
    return __builtin_elementwise_max(a, b);
}

// packed tanh: 1 - 2/(exp2(2x*log2e)+1); saturates via inf/0, no clamps
__device__ __forceinline__ f32x2 tanh_pk(f32x2 x, f32x2 k2, f32x2 one2, f32x2 m2) {
    f32x2 t = pk_mul(x, k2);
    f32x2 e;
    e.x = __builtin_amdgcn_exp2f(t.x);
    e.y = __builtin_amdgcn_exp2f(t.y);
    f32x2 dn = pk_add(e, one2);
    f32x2 r;
    r.x = __builtin_amdgcn_rcpf(dn.x);
    r.y = __builtin_amdgcn_rcpf(dn.y);
    return pk_fma(r, m2, one2);
}

// ---------------------------------------------------------------------------
// Per-step tables; one block per step i.
// ---------------------------------------------------------------------------
__global__ __launch_bounds__(128) void prep_kernel(
    const float* __restrict__ times, const float* __restrict__ freqs,
    const float* __restrict__ log_diff,
    const float* __restrict__ W1, const float* __restrict__ b1,
    const float* __restrict__ V1, const float* __restrict__ c1,
    float* __restrict__ tembW, float* __restrict__ tV,
    float* __restrict__ dtv, float* __restrict__ nsv)
{
    int j = threadIdx.x;
    int i = blockIdx.x;
    float ld = log_diff[0];
    float gb = (ld > 20.0f) ? ld : log1pf(expf(ld));  // softplus
    float t  = times[i];
    float dt = times[i + 1] - t;
    float acc = b1[j];
    #pragma unroll
    for (int m = 0; m < 16; ++m) {
        float a = 6.283185307179586f * t * freqs[m];
        float sn, cs;
        sincosf(a, &sn, &cs);
        acc = fmaf(sn, W1[(130 + m) * HD + j], acc);
        acc = fmaf(cs, W1[(146 + m) * HD + j], acc);
    }
    tembW[i * HD + j] = acc;
    tV[i * HD + j] = fmaf(t, V1[130 * HD + j], c1[j]);
    if (j == 0) {
        dtv[i] = dt;
        nsv[i] = gb * (1.0f - t) * sqrtf(fmaxf(dt, 1e-12f));
    }
}

// ---------------------------------------------------------------------------
// Pack 4 weight matrices (W1ctx, V1ctx, W2, V2) into bf16 B-fragment order:
// frag idx = ((jt*4+kt)*4+q)*16+c, element j;  k = kt*32+q*8+j, n = jt*16+c.
// (Identical A/B fragment lane maps on gfx950 mean the same data also serves
//  as the A-operand of W^T — used by the swapped L2 MFMAs in sde_kernel.)
// ---------------------------------------------------------------------------
__global__ __launch_bounds__(256) void pack_kernel(
    const float* __restrict__ W1, const float* __restrict__ V1,
    const float* __restrict__ W2, const float* __restrict__ V2,
    short* __restrict__ packed)
{
    int gi = blockIdx.x * 256 + threadIdx.x;   // 0..65535
    int mat = gi >> 14;
    int s = gi & 16383;
    int j  = s & 7;
    int cc = (s >> 3) & 15;
    int qq = (s >> 7) & 3;
    int kt = (s >> 9) & 3;
    int jt = (s >> 11) & 7;
    int k = kt * 32 + qq * 8 + j;
    int n = jt * 16 + cc;
    float v;
    if      (mat == 0) v = W1[(2 + k) * HD + n];
    else if (mat == 1) v = V1[(2 + k) * HD + n];
    else if (mat == 2) v = W2[k * HD + n];
    else               v = V2[k * HD + n];
    packed[gi] = f2bf(v);
}

// ---------------------------------------------------------------------------
// Persistent SDE kernel.  R17 (resubmit; R9 bench was an infra failure,
// "container failed twice" — no kernel signal).
// R17 = R8 (swapped-operand L2 MFMAs, lane-aligned epilogue) +
// pre-transposed W3/V3 pair tables.
// R8's regression root-cause: vx01 = {v0.x, v1.x} assembled packed pairs
// from STRIDED components -> ~64 v_mov/v_perm per step (+9% VALU cycles).
// Fix: four float4 tables in LDS, Twx/Twy/Tvx/Tvy[jt*4+q] =
// {w[j2..j2+3].comp}.  Per jt: two ds_read_b128 broadcasts; f32x2 halves of
// an f32x4 are contiguous sub-registers -> extraction free.  Values and
// accumulation order identical to R8 -> bitwise-same output.
// ---------------------------------------------------------------------------
__global__ __launch_bounds__(256, 2) void sde_kernel(
    const float* __restrict__ z0, const float* __restrict__ pctx,
    const float* __restrict__ cctx, const float* __restrict__ xi,
    const short* __restrict__ packedW,
    const float* __restrict__ W1, const float* __restrict__ V1,
    const float* __restrict__ b2, const float* __restrict__ c2,
    const float* __restrict__ W3, const float* __restrict__ b3,
    const float* __restrict__ V3, const float* __restrict__ c3,
    const float* __restrict__ tembW, const float* __restrict__ tV,
    const float* __restrict__ dtv, const float* __restrict__ nsv,
    float* __restrict__ out)
{
    __shared__ char smem[80896];            // 66K frag/stg + 5K tables + 8K tslots
    float* stg = (float*)smem;
    const bf16x8* ldsF = (const bf16x8*)smem;
    float*  zwP0s = (float*)(smem + 67584);   // W1 row0 (z.x weights), fp32
    float*  zwP1s = (float*)(smem + 68096);   // W1 row1
    float*  zwC0s = (float*)(smem + 68608);   // V1 row0
    float*  zwC1s = (float*)(smem + 69120);   // V1 row1
    float*  b2s   = (float*)(smem + 69632);
    float*  c2s   = (float*)(smem + 70144);
    float4* tbl4  = (float4*)(smem + 70656);  // Twx[0:32] Twy[32:64] Tvx[64:96] Tvy[96:128]

    int tid = threadIdx.x;
    int lane = tid & 63, wv = tid >> 6;
    int q = lane >> 4, c = lane & 15;
    int m0 = blockIdx.x * 64 + wv * 16;     // wave's 16-row base
    int mrow = m0 + c;                      // this lane's A-layout row

    // per-wave table slot: 2 buffers x 256 floats (tV[0:128] ++ tembW[128:256])
    float* tslot = (float*)(smem + 72704) + wv * 512;

    // ---- small constant tables -> LDS (covered by the phase-1 barrier) ----
    if (tid < 128) {
        zwP0s[tid] = W1[tid];
        zwP1s[tid] = W1[HD + tid];
        zwC0s[tid] = V1[tid];
        zwC1s[tid] = V1[HD + tid];
        b2s[tid] = b2[tid];
        c2s[tid] = c2[tid];
        // W3/V3 pair tables: entry e -> {src[j2+0..3][comp]}
        int sel = tid >> 5, p5 = tid & 31;       // sel: 0=Wx 1=Wy 2=Vx 3=Vy
        int jt0 = p5 >> 2, q0 = p5 & 3;
        int j2 = jt0 * 16 + q0 * 4;
        const float* wsrc = (sel < 2) ? W3 : V3;
        int comp = sel & 1;
        tbl4[tid] = make_float4(wsrc[(j2 + 0) * 2 + comp], wsrc[(j2 + 1) * 2 + comp],
                                wsrc[(j2 + 2) * 2 + comp], wsrc[(j2 + 3) * 2 + comp]);
    }

    // ---- phase 1: W1ctx/V1ctx fragments -> LDS (coalesced copy) ----
    {
        const uint4* src = (const uint4*)packedW;   // mats 0,1 = 64 KB
        uint4* dst = (uint4*)smem;
        #pragma unroll
        for (int i = 0; i < 16; ++i) dst[i * 256 + tid] = src[i * 256 + tid];
    }
    __syncthreads();

    // ---- ctx A-fragments ----
    bf16x8 pf[4], cf[4];
    #pragma unroll
    for (int kt = 0; kt < 4; ++kt) {
        const float4* p4 = (const float4*)(pctx + (size_t)mrow * HD + kt * 32 + q * 8);
        float4 a = p4[0], b = p4[1];
        uint4 tu;
        tu.x = cvt_pk_bf16(a.x, a.y); tu.y = cvt_pk_bf16(a.z, a.w);
        tu.z = cvt_pk_bf16(b.x, b.y); tu.w = cvt_pk_bf16(b.z, b.w);
        __builtin_memcpy(&pf[kt], &tu, 16);
        const float4* c4 = (const float4*)(cctx + (size_t)mrow * HD + kt * 32 + q * 8);
        float4 e = c4[0], d = c4[1];
        uint4 uu;
        uu.x = cvt_pk_bf16(e.x, e.y); uu.y = cvt_pk_bf16(e.z, e.w);
        uu.z = cvt_pk_bf16(d.x, d.y); uu.w = cvt_pk_bf16(d.z, d.w);
        __builtin_memcpy(&cf[kt], &uu, 16);
    }

    // ---- ctx projection MFMAs (step-invariant) ----
    f32x4 accP[8], accC[8];
    #pragma unroll
    for (int jt = 0; jt < 8; ++jt) {
        f32x4 ap = {0.f,0.f,0.f,0.f}, ac = {0.f,0.f,0.f,0.f};
        #pragma unroll
        for (int kt = 0; kt < 4; ++kt) {
            int fi = ((jt * 4 + kt) * 4 + q) * 16 + c;
            ap = __builtin_amdgcn_mfma_f32_16x16x32_bf16(pf[kt], ldsF[fi], ap, 0, 0, 0);
            ac = __builtin_amdgcn_mfma_f32_16x16x32_bf16(cf[kt], ldsF[2048 + fi], ac, 0, 0, 0);
        }
        accP[jt] = ap; accC[jt] = ac;
    }
    __syncthreads();

    // ---- C-layout -> A-layout round trip through LDS (once) ----
    #pragma unroll
    for (int jt = 0; jt < 8; ++jt)
        #pragma unroll
        for (int r = 0; r < 4; ++r) {
            stg[(wv * 16 + q * 4 + r) * 132 + jt * 16 + c]        = accP[jt][r];
            stg[8448 + (wv * 16 + q * 4 + r) * 132 + jt * 16 + c] = accC[jt][r];
        }
    __syncthreads();
    f32x2 projPf[16], projCf[16];   // fp32 pairs (no per-step unpack)
    #pragma unroll
    for (int kt = 0; kt < 4; ++kt) {
        const float4* rp = (const float4*)(stg + (wv * 16 + c) * 132 + kt * 32 + q * 8);
        float4 a = rp[0], b = rp[1];
        projPf[kt*4+0] = (f32x2){a.x, a.y}; projPf[kt*4+1] = (f32x2){a.z, a.w};
        projPf[kt*4+2] = (f32x2){b.x, b.y}; projPf[kt*4+3] = (f32x2){b.z, b.w};
        const float4* rc = (const float4*)(stg + 8448 + (wv * 16 + c) * 132 + kt * 32 + q * 8);
        float4 e = rc[0], d = rc[1];
        projCf[kt*4+0] = (f32x2){e.x, e.y}; projCf[kt*4+1] = (f32x2){e.z, e.w};
        projCf[kt*4+2] = (f32x2){d.x, d.y}; projCf[kt*4+3] = (f32x2){d.z, d.w};
    }
    __syncthreads();

    // ---- phase 3: W2/V2 fragments -> LDS (resident for all 50 steps) ----
    {
        const uint4* src = (const uint4*)(packedW + 32768);  // mats 2,3
        uint4* dst = (uint4*)smem;
        #pragma unroll
        for (int i = 0; i < 16; ++i) dst[i * 256 + tid] = src[i * 256 + tid];
    }
    __syncthreads();

    float b3x = b3[0] + c3[0], b3y = b3[1] + c3[1];
    const f32x2 k2    = {2.8853900817779268f, 2.8853900817779268f};
    const f32x2 one2  = {1.0f, 1.0f};
    const f32x2 m2    = {-2.0f, -2.0f};
    const f32x2 zero2 = {0.0f, 0.0f};

    const float2* z02 = (const float2*)z0;
    const float2* xi2 = (const float2*)xi;
    float2* out2 = (float2*)out;

    // ---- stage step-0 tables into buf 0 (wave-private, no barrier) ----
    {
        const float4* srcp = (lane < 32)
            ? ((const float4*)(tV) + lane)
            : ((const float4*)(tembW) + (lane - 32));
        *((float4*)tslot + lane) = *srcp;
    }

    float2 zi = z02[mrow];
    float zx = zi.x, zy = zi.y;          // z for particle c (all 4 q-copies)
    if (lane < 16) out2[m0 + lane] = make_float2(zx, zy);   // lane l holds row l

    const f32x4* Twx = (const f32x4*)tbl4;
    const f32x4* Twy = Twx + 32;
    const f32x4* Tvx = Twx + 64;
    const f32x4* Tvy = Twx + 96;

    for (int i = 0; i < TSTEPS; ++i) {
        int b = i & 1;
        const float* tb = tslot + b * 256;

        // prefetch next step's table slice (consumed at end of step)
        int sN = (i + 1 < TSTEPS) ? i + 1 : i;
        float4 pfv;
        {
            const float4* srcp = (lane < 32)
                ? ((const float4*)(tV + sN * HD) + lane)
                : ((const float4*)(tembW + sN * HD) + (lane - 32));
            pfv = *srcp;
        }
        // xi + step scalars, hoisted (particle c; 4 q-copies load same addr)
        float dt = dtv[i], ns = nsv[i];
        float2 xiv = xi2[(size_t)i * NP + m0 + c];

        f32x2 zx2 = {zx, zx}, zy2 = {zy, zy};
        f32x2 px2 = zero2, py2 = zero2;   // particle-c drift partials (pairs)

        // ===== cnf MLP: tanh, V-weights (LDS slot 1) =====
        bf16x8 af[4];
        #pragma unroll
        for (int kt = 0; kt < 4; ++kt) {
            const f32x2* tvp = (const f32x2*)(tb + kt * 32 + q * 8);
            const f32x2* w0p = (const f32x2*)(zwC0s + kt * 32 + q * 8);
            const f32x2* w1p = (const f32x2*)(zwC1s + kt * 32 + q * 8);
            uint4 tu;
            unsigned uu[4];
            #pragma unroll
            for (int p = 0; p < 4; ++p) {
                f32x2 lin = pk_add(projCf[kt * 4 + p], tvp[p]);
                lin = pk_fma(zx2, w0p[p], lin);
                lin = pk_fma(zy2, w1p[p], lin);
                f32x2 th = tanh_pk(lin, k2, one2, m2);
                uu[p] = cvt_pk_bf16(th.x, th.y);
            }
            tu.x = uu[0]; tu.y = uu[1]; tu.z = uu[2]; tu.w = uu[3];
            __builtin_memcpy(&af[kt], &tu, 16);
        }
        #pragma unroll
        for (int jt = 0; jt < 8; ++jt) {
            // swapped operands: h2^T; rows j2 = jt*16+q*4+r, col = particle c.
            // bias c2 enters as C-input (row-indexed float4).
            const float4 cb4 = *(const float4*)(c2s + jt * 16 + q * 4);
            f32x4 acc = {cb4.x, cb4.y, cb4.z, cb4.w};
            #pragma unroll
            for (int kt = 0; kt < 4; ++kt)
                acc = __builtin_amdgcn_mfma_f32_16x16x32_bf16(
                    ldsF[2048 + ((jt * 4 + kt) * 4 + q) * 16 + c], af[kt], acc, 0, 0, 0);
            f32x2 h01 = tanh_pk((f32x2){acc[0], acc[1]}, k2, one2, m2);
            f32x2 h23 = tanh_pk((f32x2){acc[2], acc[3]}, k2, one2, m2);
            f32x4 vx = Tvx[jt * 4 + q];             // one ds_read_b128, broadcast
            f32x4 vy = Tvy[jt * 4 + q];
            f32x2 vx01 = {vx[0], vx[1]}, vx23 = {vx[2], vx[3]};   // free sub-reg
            f32x2 vy01 = {vy[0], vy[1]}, vy23 = {vy[2], vy[3]};
            px2 = pk_fma(h01, vx01, px2); px2 = pk_fma(h23, vx23, px2);
            py2 = pk_fma(h01, vy01, py2); py2 = pk_fma(h23, vy23, py2);
        }

        // ===== post MLP: relu, W-weights (LDS slot 0) =====
        #pragma unroll
        for (int kt = 0; kt < 4; ++kt) {
            const f32x2* tvp = (const f32x2*)(tb + 128 + kt * 32 + q * 8);
            const f32x2* w0p = (const f32x2*)(zwP0s + kt * 32 + q * 8);
            const f32x2* w1p = (const f32x2*)(zwP1s + kt * 32 + q * 8);
            uint4 tu;
            unsigned uu[4];
            #pragma unroll
            for (int p = 0; p < 4; ++p) {
                f32x2 lin = pk_add(projPf[kt * 4 + p], tvp[p]);
                lin = pk_fma(zx2, w0p[p], lin);
                lin = pk_fma(zy2, w1p[p], lin);
                f32x2 th = pk_max(lin, zero2);
                uu[p] = cvt_pk_bf16(th.x, th.y);
            }
            tu.x = uu[0]; tu.y = uu[1]; tu.z = uu[2]; tu.w = uu[3];
            __builtin_memcpy(&af[kt], &tu, 16);
        }
        #pragma unroll
        for (int jt = 0; jt < 8; ++jt) {
            const float4 bb4 = *(const float4*)(b2s + jt * 16 + q * 4);
            f32x4 acc = {bb4.x, bb4.y, bb4.z, bb4.w};
            #pragma unroll
            for (int kt = 0; kt < 4; ++kt)
                acc = __builtin_amdgcn_mfma_f32_16x16x32_bf16(
                    ldsF[((jt * 4 + kt) * 4 + q) * 16 + c], af[kt], acc, 0, 0, 0);
            f32x2 h01 = pk_max((f32x2){acc[0], acc[1]}, zero2);
            f32x2 h23 = pk_max((f32x2){acc[2], acc[3]}, zero2);
            f32x4 wx = Twx[jt * 4 + q];
            f32x4 wy = Twy[jt * 4 + q];
            f32x2 wx01 = {wx[0], wx[1]}, wx23 = {wx[2], wx[3]};
            f32x2 wy01 = {wy[0], wy[1]}, wy23 = {wy[2], wy[3]};
            px2 = pk_fma(h01, wx01, px2); px2 = pk_fma(h23, wx23, px2);
            py2 = pk_fma(h01, wy01, py2); py2 = pk_fma(h23, wy23, py2);
        }

        // write prefetched tables to the other buffer (global load had the
        // whole step to land; next iteration's ds_reads sync via lgkmcnt)
        *((float4*)(tslot + (b ^ 1) * 256) + lane) = pfv;

        // ===== reduce over the 4 q-copies (lanes c, 16+c, 32+c, 48+c) =====
        float sdx = px2.x + px2.y + b3x;
        float sdy = py2.x + py2.y + b3y;
        sdx += __shfl_xor(sdx, 16);
        sdy += __shfl_xor(sdy, 16);
        sdx += __shfl_xor(sdx, 32);
        sdy += __shfl_xor(sdy, 32);

        // ===== z update: lane c holds particle c; all q-copies identical ====
        float znx = fmaf(sdx, dt, zx) + xiv.x * ns;
        float zny = fmaf(sdy, dt, zy) + xiv.y * ns;
        if (lane < 16) out2[(size_t)(i + 1) * NP + m0 + lane] = make_float2(znx, zny);
        zx = znx;
        zy = zny;
    }
}

extern "C" void kernel_launch(void* const* d_in, const int* in_sizes, int n_in,
                              void* d_out, int out_size, void* d_ws, size_t ws_size,
                              hipStream_t stream)
{
    const float* z0    = (const float*)d_in[0];
    const float* pctx  = (const float*)d_in[1];
    const float* cctx  = (const float*)d_in[2];
    const float* times = (const float*)d_in[3];
    const float* xi    = (const float*)d_in[4];
    const float* freqs = (const float*)d_in[5];
    const float* logd  = (const float*)d_in[6];
    const float* W1 = (const float*)d_in[7];
    const float* b1 = (const float*)d_in[8];
    const float* W2 = (const float*)d_in[9];
    const float* b2 = (const float*)d_in[10];
    const float* W3 = (const float*)d_in[11];
    const float* b3 = (const float*)d_in[12];
    const float* V1 = (const float*)d_in[13];
    const float* c1 = (const float*)d_in[14];
    const float* V2 = (const float*)d_in[15];
    const float* c2 = (const float*)d_in[16];
    const float* V3 = (const float*)d_in[17];
    const float* c3 = (const float*)d_in[18];

    short* packedW = (short*)d_ws;                       // 4 x 16384 shorts = 128 KB
    float* tembW = (float*)((char*)d_ws + 131072);       // [50][128]
    float* tV    = tembW + TSTEPS * HD;                  // [50][128]
    float* dtv   = tV + TSTEPS * HD;
    float* nsv   = dtv + 64;

    prep_kernel<<<TSTEPS, 128, 0, stream>>>(times, freqs, logd, W1, b1, V1, c1,
                                            tembW, tV, dtv, nsv);
    pack_kernel<<<256, 256, 0, stream>>>(W1, V1, W2, V2, packedW);
    sde_kernel<<<NP / 64, 256, 0, stream>>>(z0, pctx, cctx, xi, packedW,
                                            W1, V1, b2, c2, W3, b3, V3, c3,
                                            tembW, tV, dtv, nsv,
                                            (float*)d_out);
}